// Round 1
// baseline (2578.528 us; speedup 1.0000x reference)
//
#include <hip/hip_runtime.h>
#include <hip/hip_bf16.h>
#include <math.h>

// Problem constants
#define B_    32
#define DIM_  64
#define NP_   4
#define D_    1024
#define E_    768
#define VC_   32000
#define R_    2048          // B_*DIM_
#define KTOP  2
#define EPS_  1e-8f
#define NCB   250           // 32000 / 128 col-blocks in scores GEMM

// Workspace layout (in floats)
#define T_OFF    ((size_t)0)
#define T_SZ     ((size_t)VC_ * D_)               // 32,768,000
#define S_OFF    (T_OFF + T_SZ)
#define S_SZ     ((size_t)R_ * D_)                // 2,097,152
#define INVW_OFF (S_OFF + S_SZ)
#define INVP_OFF (INVW_OFF + VC_)
#define PV_OFF   (INVP_OFF + R_)
#define PV_SZ    ((size_t)R_ * NCB * 2)           // 1,024,000
#define PI_OFF   (PV_OFF + PV_SZ)
#define TI_OFF   (PI_OFF + PV_SZ)                 // int top-2 indices, R_*2

#define NEG_INF (-3.4e38f)

// ---------------------------------------------------------------------------
// Kernel A: s[r,d] = sum_np P[r,np,d];  invp[r] = 1/max(||P[r,:,:]||, eps)
// ---------------------------------------------------------------------------
__global__ __launch_bounds__(256) void k_sum_pnorm(const float* __restrict__ P,
                                                   float* __restrict__ s,
                                                   float* __restrict__ invp) {
    int r = blockIdx.x;
    int t = threadIdx.x;
    const float* base = P + (size_t)r * NP_ * D_;
    float4 acc = make_float4(0.f, 0.f, 0.f, 0.f);
    float sq = 0.f;
#pragma unroll
    for (int np = 0; np < NP_; ++np) {
        float4 v = *(const float4*)(base + (size_t)np * D_ + t * 4);
        acc.x += v.x; acc.y += v.y; acc.z += v.z; acc.w += v.w;
        sq += v.x * v.x + v.y * v.y + v.z * v.z + v.w * v.w;
    }
    *(float4*)(s + (size_t)r * D_ + t * 4) = acc;

    __shared__ float red[256];
    red[t] = sq;
    __syncthreads();
    for (int off = 128; off > 0; off >>= 1) {
        if (t < off) red[t] += red[t + off];
        __syncthreads();
    }
    if (t == 0) {
        float pn = fmaxf(sqrtf(red[0]), EPS_);
        invp[r] = 1.0f / pn;
    }
}

// ---------------------------------------------------------------------------
// Kernel B: T[v,d] = dot(fe_w[v,:], we[d,:]) + fe_b[v]
// 128x128 tile, BK=16, 256 threads, 8x8 per-thread microtile
// ---------------------------------------------------------------------------
__global__ __launch_bounds__(256) void k_gemm_T(const float* __restrict__ A,   // fe_w [VC,E]
                                                const float* __restrict__ Bm,  // we   [D,E]
                                                const float* __restrict__ bias,
                                                float* __restrict__ T) {
    __shared__ float As[16][132];  // As[k][row]
    __shared__ float Bs[16][132];
    int tid = threadIdx.x;
    int tx = tid & 15, ty = tid >> 4;
    int v0 = blockIdx.y * 128;
    int d0 = blockIdx.x * 128;
    float acc[8][8] = {};

    for (int k0 = 0; k0 < E_; k0 += 16) {
#pragma unroll
        for (int it = 0; it < 2; ++it) {
            int f = tid + it * 256;
            int row = f >> 2, kq = (f & 3) << 2;
            float4 va = *(const float4*)(A + (size_t)(v0 + row) * E_ + k0 + kq);
            As[kq + 0][row] = va.x; As[kq + 1][row] = va.y;
            As[kq + 2][row] = va.z; As[kq + 3][row] = va.w;
            float4 vb = *(const float4*)(Bm + (size_t)(d0 + row) * E_ + k0 + kq);
            Bs[kq + 0][row] = vb.x; Bs[kq + 1][row] = vb.y;
            Bs[kq + 2][row] = vb.z; Bs[kq + 3][row] = vb.w;
        }
        __syncthreads();
#pragma unroll
        for (int k = 0; k < 16; ++k) {
            float a[8], b[8];
            *(float4*)&a[0] = *(const float4*)&As[k][ty * 8];
            *(float4*)&a[4] = *(const float4*)&As[k][ty * 8 + 4];
            *(float4*)&b[0] = *(const float4*)&Bs[k][tx * 8];
            *(float4*)&b[4] = *(const float4*)&Bs[k][tx * 8 + 4];
#pragma unroll
            for (int i = 0; i < 8; ++i)
#pragma unroll
                for (int j = 0; j < 8; ++j) acc[i][j] += a[i] * b[j];
        }
        __syncthreads();
    }
#pragma unroll
    for (int i = 0; i < 8; ++i) {
        int v = v0 + ty * 8 + i;
        float bv = bias[v];
#pragma unroll
        for (int j = 0; j < 8; j += 4) {
            float4 o = make_float4(acc[i][j] + bv, acc[i][j + 1] + bv,
                                   acc[i][j + 2] + bv, acc[i][j + 3] + bv);
            *(float4*)(T + (size_t)v * D_ + d0 + tx * 8 + j) = o;
        }
    }
}

// ---------------------------------------------------------------------------
// Kernel W: invw[v] = 1 / max(sqrt(NP)*||T[v,:]||, eps)
// ---------------------------------------------------------------------------
__global__ __launch_bounds__(256) void k_wnorm(const float* __restrict__ T,
                                               float* __restrict__ invw) {
    int v = blockIdx.x;
    int t = threadIdx.x;
    float4 x = *(const float4*)(T + (size_t)v * D_ + t * 4);
    float sq = x.x * x.x + x.y * x.y + x.z * x.z + x.w * x.w;
    __shared__ float red[256];
    red[t] = sq;
    __syncthreads();
    for (int off = 128; off > 0; off >>= 1) {
        if (t < off) red[t] += red[t + off];
        __syncthreads();
    }
    if (t == 0) {
        float wn = fmaxf(2.0f * sqrtf(red[0]), EPS_);  // sqrt(NP_)=2
        invw[v] = 1.0f / wn;
    }
}

// ---------------------------------------------------------------------------
// Kernel C: scores GEMM [2048 x 32000], K=1024, fused per-tile top-2
// ---------------------------------------------------------------------------
__device__ __forceinline__ bool better(float v, int i, float bv, int bi) {
    return (v > bv) || (v == bv && i < bi);
}

__global__ __launch_bounds__(256) void k_scores(const float* __restrict__ s,   // [R,D]
                                                const float* __restrict__ T,   // [VC,D]
                                                const float* __restrict__ invw,
                                                const float* __restrict__ invp,
                                                float* __restrict__ pval,
                                                int* __restrict__ pidx) {
    __shared__ float As[16][132];
    __shared__ float Bs[16][132];
    __shared__ float cv[128][16][2];
    __shared__ int   ci[128][16][2];
    int tid = threadIdx.x;
    int tx = tid & 15, ty = tid >> 4;
    int r0 = blockIdx.y * 128;
    int v0 = blockIdx.x * 128;
    float acc[8][8] = {};

    for (int k0 = 0; k0 < D_; k0 += 16) {
#pragma unroll
        for (int it = 0; it < 2; ++it) {
            int f = tid + it * 256;
            int row = f >> 2, kq = (f & 3) << 2;
            float4 va = *(const float4*)(s + (size_t)(r0 + row) * D_ + k0 + kq);
            As[kq + 0][row] = va.x; As[kq + 1][row] = va.y;
            As[kq + 2][row] = va.z; As[kq + 3][row] = va.w;
            float4 vb = *(const float4*)(T + (size_t)(v0 + row) * D_ + k0 + kq);
            Bs[kq + 0][row] = vb.x; Bs[kq + 1][row] = vb.y;
            Bs[kq + 2][row] = vb.z; Bs[kq + 3][row] = vb.w;
        }
        __syncthreads();
#pragma unroll
        for (int k = 0; k < 16; ++k) {
            float a[8], b[8];
            *(float4*)&a[0] = *(const float4*)&As[k][ty * 8];
            *(float4*)&a[4] = *(const float4*)&As[k][ty * 8 + 4];
            *(float4*)&b[0] = *(const float4*)&Bs[k][tx * 8];
            *(float4*)&b[4] = *(const float4*)&Bs[k][tx * 8 + 4];
#pragma unroll
            for (int i = 0; i < 8; ++i)
#pragma unroll
                for (int j = 0; j < 8; ++j) acc[i][j] += a[i] * b[j];
        }
        __syncthreads();
    }

    // Epilogue: scale + per-thread top-2 over the 8 columns of each of 8 rows
    float iw[8];
#pragma unroll
    for (int j = 0; j < 8; ++j) iw[j] = invw[v0 + tx * 8 + j];
#pragma unroll
    for (int i = 0; i < 8; ++i) {
        int row = ty * 8 + i;
        float ip = invp[r0 + row];
        float b1 = NEG_INF, b2 = NEG_INF;
        int i1 = 0x7fffffff, i2 = 0x7fffffff;
#pragma unroll
        for (int j = 0; j < 8; ++j) {
            int v = v0 + tx * 8 + j;
            float val = acc[i][j] * iw[j] * ip;
            if (better(val, v, b1, i1)) { b2 = b1; i2 = i1; b1 = val; i1 = v; }
            else if (better(val, v, b2, i2)) { b2 = val; i2 = v; }
        }
        cv[row][tx][0] = b1; ci[row][tx][0] = i1;
        cv[row][tx][1] = b2; ci[row][tx][1] = i2;
    }
    __syncthreads();

    if (tid < 128) {
        int row = tid;
        float b1 = NEG_INF, b2 = NEG_INF;
        int i1 = 0x7fffffff, i2 = 0x7fffffff;
#pragma unroll 4
        for (int x = 0; x < 16; ++x) {
            for (int sslot = 0; sslot < 2; ++sslot) {
                float v = cv[row][x][sslot];
                int id = ci[row][x][sslot];
                if (better(v, id, b1, i1)) { b2 = b1; i2 = i1; b1 = v; i1 = id; }
                else if (better(v, id, b2, i2)) { b2 = v; i2 = id; }
            }
        }
        int r = r0 + row;
        int cb = blockIdx.x;
        size_t o = ((size_t)r * NCB + cb) * 2;
        pval[o + 0] = b1; pidx[o + 0] = i1;
        pval[o + 1] = b2; pidx[o + 1] = i2;
    }
}

// ---------------------------------------------------------------------------
// Kernel D: merge 250 partial top-2s per row -> final top-2; write values
// ---------------------------------------------------------------------------
__global__ __launch_bounds__(256) void k_topk_final(const float* __restrict__ pval,
                                                    const int* __restrict__ pidx,
                                                    float* __restrict__ outv,  // [R,2]
                                                    int* __restrict__ tidx) {  // [R,2]
    int r = blockIdx.x;
    int t = threadIdx.x;
    const int NC = NCB * 2;  // 500
    float b1 = NEG_INF, b2 = NEG_INF;
    int i1 = 0x7fffffff, i2 = 0x7fffffff;
    for (int c = t; c < NC; c += 256) {
        float v = pval[(size_t)r * NC + c];
        int id = pidx[(size_t)r * NC + c];
        if (better(v, id, b1, i1)) { b2 = b1; i2 = i1; b1 = v; i1 = id; }
        else if (better(v, id, b2, i2)) { b2 = v; i2 = id; }
    }
    __shared__ float sv[256][2];
    __shared__ int si[256][2];
    sv[t][0] = b1; si[t][0] = i1;
    sv[t][1] = b2; si[t][1] = i2;
    __syncthreads();
    if (t == 0) {
        float f1 = NEG_INF, f2 = NEG_INF;
        int j1 = 0x7fffffff, j2 = 0x7fffffff;
        for (int x = 0; x < 256; ++x) {
            for (int sl = 0; sl < 2; ++sl) {
                float v = sv[x][sl];
                int id = si[x][sl];
                if (better(v, id, f1, j1)) { f2 = f1; j2 = j1; f1 = v; j1 = id; }
                else if (better(v, id, f2, j2)) { f2 = v; j2 = id; }
            }
        }
        outv[(size_t)r * 2 + 0] = f1;
        outv[(size_t)r * 2 + 1] = f2;
        tidx[r * 2 + 0] = j1;
        tidx[r * 2 + 1] = j2;
    }
}

// ---------------------------------------------------------------------------
// Kernel E: Z[r, 0:2, :] = T[idx], Z[r, 2:6, :] = P[r, :, :]
// ---------------------------------------------------------------------------
__global__ __launch_bounds__(256) void k_writeZ(const float* __restrict__ P,
                                                const float* __restrict__ T,
                                                const int* __restrict__ tidx,
                                                float* __restrict__ out) {
    int blk = blockIdx.x;  // r*6 + j
    int r = blk / 6, j = blk - r * 6;
    const float* src;
    if (j < KTOP) src = T + (size_t)tidx[r * 2 + j] * D_;
    else          src = P + ((size_t)r * NP_ + (j - KTOP)) * D_;
    float4 v = *(const float4*)(src + threadIdx.x * 4);
    *(float4*)(out + ((size_t)r * 6 + j) * D_ + threadIdx.x * 4) = v;
}

// ---------------------------------------------------------------------------
extern "C" void kernel_launch(void* const* d_in, const int* in_sizes, int n_in,
                              void* d_out, int out_size, void* d_ws, size_t ws_size,
                              hipStream_t stream) {
    const float* P   = (const float*)d_in[0];  // [32,64,4,1024]
    const float* we  = (const float*)d_in[1];  // [1024,768]
    const float* few = (const float*)d_in[2];  // [32000,768]
    const float* feb = (const float*)d_in[3];  // [32000]
    float* out = (float*)d_out;                // Z (12,582,912) then values (4096)
    float* ws  = (float*)d_ws;

    float* T    = ws + T_OFF;
    float* s    = ws + S_OFF;
    float* invw = ws + INVW_OFF;
    float* invp = ws + INVP_OFF;
    float* pval = ws + PV_OFF;
    int*   pidx = (int*)(ws + PI_OFF);
    int*   tidx = (int*)(ws + TI_OFF);
    float* outv = out + (size_t)R_ * 6 * D_;

    k_sum_pnorm<<<R_, 256, 0, stream>>>(P, s, invp);
    k_gemm_T<<<dim3(D_ / 128, VC_ / 128), 256, 0, stream>>>(few, we, feb, T);
    k_wnorm<<<VC_, 256, 0, stream>>>(T, invw);
    k_scores<<<dim3(VC_ / 128, R_ / 128), 256, 0, stream>>>(s, T, invw, invp, pval, pidx);
    k_topk_final<<<R_, 256, 0, stream>>>(pval, pidx, outv, tidx);
    k_writeZ<<<R_ * 6, 256, 0, stream>>>(P, T, tidx, out);
}

// Round 2
// 1143.844 us; speedup vs baseline: 2.2543x; 2.2543x over previous
//
#include <hip/hip_runtime.h>
#include <hip/hip_bf16.h>
#include <math.h>

// Problem constants
#define B_    32
#define DIM_  64
#define NP_   4
#define D_    1024
#define E_    768
#define VC_   32000
#define R_    2048          // B_*DIM_
#define KTOP  2
#define EPS_  1e-8f
#define NCB   250           // 32000 / 128 v-blocks in scores GEMM
#define NCAND 8

// Workspace layout (float offsets)
#define T_OFF    ((size_t)0)
#define S_OFF    (T_OFF + (size_t)VC_ * D_)          // 32,768,000
#define INVW_OFF (S_OFF + (size_t)R_ * D_)           // 34,865,152
#define INVP_OFF (INVW_OFF + VC_)                    // 34,897,152
#define PV_OFF   (INVP_OFF + R_)                     // 34,899,200
#define PI_OFF   (PV_OFF + (size_t)R_ * NCB * 2)     // 35,923,200
#define SB_OFF   (PI_OFF + (size_t)R_ * NCB * 2)     // 36,947,200  (ushort region, R_*D_ ushorts)
#define TB_OFF   (SB_OFF + (size_t)R_ * D_ / 2)      // 37,995,776  (ushort region, VC_*D_ ushorts)
#define CAND_OFF (TB_OFF + (size_t)VC_ * D_ / 2)     // 54,379,776  (int region, R_*8)
#define TIDX_OFF (CAND_OFF + (size_t)R_ * NCAND)     // 54,396,160
// total ~54,400,256 floats = 217.6 MB

#define NEG_INF (-3.4e38f)

typedef __bf16 bf16x8 __attribute__((ext_vector_type(8)));
typedef float  f32x4  __attribute__((ext_vector_type(4)));

__device__ __forceinline__ unsigned short f2bf(float f) {
    unsigned u = __float_as_uint(f);
    u += 0x7fffu + ((u >> 16) & 1u);           // round-to-nearest-even
    return (unsigned short)(u >> 16);
}

// global -> LDS direct copy, 16B per lane. LDS dest = wave-uniform base + lane*16.
__device__ __forceinline__ void async_ld16(const void* gptr, void* lptr) {
    __builtin_amdgcn_global_load_lds(
        (const __attribute__((address_space(1))) void*)(uintptr_t)gptr,
        (__attribute__((address_space(3))) void*)(unsigned)(uintptr_t)lptr,
        16, 0, 0);
}

__device__ __forceinline__ bool better(float v, int i, float bv, int bi) {
    return (v > bv) || (v == bv && i < bi);
}

// ---------------------------------------------------------------------------
// Kernel A: s[r,d] = sum_np P[r,np,d]; sb = bf16(s); invp[r] = 1/max(||P_r||,eps)
// ---------------------------------------------------------------------------
__global__ __launch_bounds__(256) void k_sum_pnorm(const float* __restrict__ P,
                                                   float* __restrict__ s,
                                                   unsigned short* __restrict__ sb,
                                                   float* __restrict__ invp) {
    int r = blockIdx.x;
    int t = threadIdx.x;
    const float* base = P + (size_t)r * NP_ * D_;
    float4 acc = make_float4(0.f, 0.f, 0.f, 0.f);
    float sq = 0.f;
#pragma unroll
    for (int np = 0; np < NP_; ++np) {
        float4 v = *(const float4*)(base + (size_t)np * D_ + t * 4);
        acc.x += v.x; acc.y += v.y; acc.z += v.z; acc.w += v.w;
        sq += v.x * v.x + v.y * v.y + v.z * v.z + v.w * v.w;
    }
    *(float4*)(s + (size_t)r * D_ + t * 4) = acc;
    ushort4 o;
    o.x = f2bf(acc.x); o.y = f2bf(acc.y); o.z = f2bf(acc.z); o.w = f2bf(acc.w);
    *(ushort4*)(sb + (size_t)r * D_ + t * 4) = o;

    __shared__ float red[256];
    red[t] = sq;
    __syncthreads();
    for (int off = 128; off > 0; off >>= 1) {
        if (t < off) red[t] += red[t + off];
        __syncthreads();
    }
    if (t == 0) invp[r] = 1.0f / fmaxf(sqrtf(red[0]), EPS_);
}

// ---------------------------------------------------------------------------
// Kernel B: T[v,d] = dot(fe_w[v,:], we[d,:]) + fe_b[v]   (fp32-exact path)
// ---------------------------------------------------------------------------
__global__ __launch_bounds__(256) void k_gemm_T(const float* __restrict__ A,   // fe_w [VC,E]
                                                const float* __restrict__ Bm,  // we   [D,E]
                                                const float* __restrict__ bias,
                                                float* __restrict__ T) {
    __shared__ float As[16][132];
    __shared__ float Bs[16][132];
    int tid = threadIdx.x;
    int tx = tid & 15, ty = tid >> 4;
    int v0 = blockIdx.y * 128;
    int d0 = blockIdx.x * 128;
    float acc[8][8] = {};

    for (int k0 = 0; k0 < E_; k0 += 16) {
#pragma unroll
        for (int it = 0; it < 2; ++it) {
            int f = tid + it * 256;
            int row = f >> 2, kq = (f & 3) << 2;
            float4 va = *(const float4*)(A + (size_t)(v0 + row) * E_ + k0 + kq);
            As[kq + 0][row] = va.x; As[kq + 1][row] = va.y;
            As[kq + 2][row] = va.z; As[kq + 3][row] = va.w;
            float4 vb = *(const float4*)(Bm + (size_t)(d0 + row) * E_ + k0 + kq);
            Bs[kq + 0][row] = vb.x; Bs[kq + 1][row] = vb.y;
            Bs[kq + 2][row] = vb.z; Bs[kq + 3][row] = vb.w;
        }
        __syncthreads();
#pragma unroll
        for (int k = 0; k < 16; ++k) {
            float a[8], b[8];
            *(float4*)&a[0] = *(const float4*)&As[k][ty * 8];
            *(float4*)&a[4] = *(const float4*)&As[k][ty * 8 + 4];
            *(float4*)&b[0] = *(const float4*)&Bs[k][tx * 8];
            *(float4*)&b[4] = *(const float4*)&Bs[k][tx * 8 + 4];
#pragma unroll
            for (int i = 0; i < 8; ++i)
#pragma unroll
                for (int j = 0; j < 8; ++j) acc[i][j] += a[i] * b[j];
        }
        __syncthreads();
    }
#pragma unroll
    for (int i = 0; i < 8; ++i) {
        int v = v0 + ty * 8 + i;
        float bv = bias[v];
#pragma unroll
        for (int j = 0; j < 8; j += 4) {
            float4 o = make_float4(acc[i][j] + bv, acc[i][j + 1] + bv,
                                   acc[i][j + 2] + bv, acc[i][j + 3] + bv);
            *(float4*)(T + (size_t)v * D_ + d0 + tx * 8 + j) = o;
        }
    }
}

// ---------------------------------------------------------------------------
// Kernel W: invw[v] = 1 / max(2*||T[v,:]||, eps)
// ---------------------------------------------------------------------------
__global__ __launch_bounds__(256) void k_wnorm(const float* __restrict__ T,
                                               float* __restrict__ invw) {
    int v = blockIdx.x;
    int t = threadIdx.x;
    float4 x = *(const float4*)(T + (size_t)v * D_ + t * 4);
    float sq = x.x * x.x + x.y * x.y + x.z * x.z + x.w * x.w;
    __shared__ float red[256];
    red[t] = sq;
    __syncthreads();
    for (int off = 128; off > 0; off >>= 1) {
        if (t < off) red[t] += red[t + off];
        __syncthreads();
    }
    if (t == 0) invw[v] = 1.0f / fmaxf(2.0f * sqrtf(red[0]), EPS_);
}

// ---------------------------------------------------------------------------
// Kernel Tb: Tb[v,k] = bf16(T[v,k] * invw[v])  -- invw folded so candidate
// ranking per row r needs no per-element scaling at all.
// ---------------------------------------------------------------------------
__global__ __launch_bounds__(128) void k_make_tb(const float* __restrict__ T,
                                                 const float* __restrict__ invw,
                                                 unsigned short* __restrict__ Tb) {
    int v = blockIdx.x, t = threadIdx.x;
    float iw = invw[v];
    const float* src = T + (size_t)v * D_ + t * 8;
    float4 a = *(const float4*)src;
    float4 b = *(const float4*)(src + 4);
    ushort4 oa, ob;
    oa.x = f2bf(a.x * iw); oa.y = f2bf(a.y * iw); oa.z = f2bf(a.z * iw); oa.w = f2bf(a.w * iw);
    ob.x = f2bf(b.x * iw); ob.y = f2bf(b.y * iw); ob.z = f2bf(b.z * iw); ob.w = f2bf(b.w * iw);
    *(ushort4*)(Tb + (size_t)v * D_ + t * 8) = oa;
    *(ushort4*)(Tb + (size_t)v * D_ + t * 8 + 4) = ob;
}

// ---------------------------------------------------------------------------
// Kernel C: bf16 MFMA candidate GEMM. Tile 128(v) x 128(r), BK=32.
// First operand = Tb rows (m=v), second = sb rows (n=r).
// D layout: col(lane&15)=r, row(quad*4+reg)=v  -> per-lane top-2 over 16 v's.
// Emits per-(r, v-block) top-2 partials (approx values, used only to nominate).
// ---------------------------------------------------------------------------
__global__ __launch_bounds__(256) void k_scores_mfma(const unsigned short* __restrict__ Tb,
                                                     const unsigned short* __restrict__ sb,
                                                     float* __restrict__ pval,
                                                     int* __restrict__ pidx) {
    __shared__ __align__(16) unsigned short As[128 * 32];  // [v-row][k] 64B rows
    __shared__ __align__(16) unsigned short Bs[128 * 32];  // [r-row][k]
    __shared__ float mv[2][128][2];
    __shared__ int   mi[2][128][2];

    int tid = threadIdx.x;
    int wid = tid >> 6, lane = tid & 63;
    int quad = lane >> 4, l15 = lane & 15;
    int v0 = blockIdx.x * 128;
    int r0 = blockIdx.y * 128;
    int vband = (wid & 1) * 64, rband = (wid >> 1) * 64;

    f32x4 acc[4][4];
#pragma unroll
    for (int i = 0; i < 4; ++i)
#pragma unroll
        for (int j = 0; j < 4; ++j) acc[i][j] = f32x4{0.f, 0.f, 0.f, 0.f};

    int srow  = wid * 32 + (lane >> 2);   // staging row (j adds 16)
    int skoff = (lane & 3) * 8;           // staging k offset (elems)

    for (int k0 = 0; k0 < D_; k0 += 32) {
#pragma unroll
        for (int j = 0; j < 2; ++j) {
            const unsigned short* ga = Tb + (size_t)(v0 + srow + j * 16) * D_ + k0 + skoff;
            async_ld16(ga, (void*)(As + (wid * 32 + j * 16) * 32));
            const unsigned short* gb = sb + (size_t)(r0 + srow + j * 16) * D_ + k0 + skoff;
            async_ld16(gb, (void*)(Bs + (wid * 32 + j * 16) * 32));
        }
        __syncthreads();   // drains vmcnt before any wave reads the tiles
        bf16x8 af[4], bf[4];
#pragma unroll
        for (int mt = 0; mt < 4; ++mt)
            af[mt] = *(const bf16x8*)(As + (vband + mt * 16 + l15) * 32 + quad * 8);
#pragma unroll
        for (int nt = 0; nt < 4; ++nt)
            bf[nt] = *(const bf16x8*)(Bs + (rband + nt * 16 + l15) * 32 + quad * 8);
#pragma unroll
        for (int mt = 0; mt < 4; ++mt)
#pragma unroll
            for (int nt = 0; nt < 4; ++nt)
                acc[mt][nt] = __builtin_amdgcn_mfma_f32_16x16x32_bf16(af[mt], bf[nt], acc[mt][nt], 0, 0, 0);
        __syncthreads();   // tiles consumed; safe to overwrite next iter
    }

    // Epilogue: per r, top-2 over this block's 128 v's.
#pragma unroll
    for (int nt = 0; nt < 4; ++nt) {
        float b1 = NEG_INF, b2 = NEG_INF;
        int i1 = 0x7fffffff, i2 = 0x7fffffff;
#pragma unroll
        for (int mt = 0; mt < 4; ++mt)
#pragma unroll
            for (int rg = 0; rg < 4; ++rg) {
                float val = acc[mt][nt][rg];
                int v = v0 + vband + mt * 16 + quad * 4 + rg;
                if (better(val, v, b1, i1)) { b2 = b1; i2 = i1; b1 = val; i1 = v; }
                else if (better(val, v, b2, i2)) { b2 = val; i2 = v; }
            }
        // butterfly across the 4 quads (same r = lane&15 preserved)
#pragma unroll
        for (int off = 16; off <= 32; off <<= 1) {
            float o1 = __shfl_xor(b1, off), o2 = __shfl_xor(b2, off);
            int  oi1 = __shfl_xor(i1, off), oi2 = __shfl_xor(i2, off);
            if (better(o1, oi1, b1, i1)) {
                if (better(b1, i1, o2, oi2)) { b2 = b1; i2 = i1; } else { b2 = o2; i2 = oi2; }
                b1 = o1; i1 = oi1;
            } else if (better(o1, oi1, b2, i2)) { b2 = o1; i2 = oi1; }
        }
        if (quad == 0) {
            int rl = rband + nt * 16 + l15;
            mv[wid & 1][rl][0] = b1; mi[wid & 1][rl][0] = i1;
            mv[wid & 1][rl][1] = b2; mi[wid & 1][rl][1] = i2;
        }
    }
    __syncthreads();
    if (tid < 128) {
        float b1 = mv[0][tid][0], b2 = mv[0][tid][1];
        int   i1 = mi[0][tid][0], i2 = mi[0][tid][1];
#pragma unroll
        for (int sl = 0; sl < 2; ++sl) {
            float o = mv[1][tid][sl]; int oi = mi[1][tid][sl];
            if (better(o, oi, b1, i1)) { b2 = b1; i2 = i1; b1 = o; i1 = oi; }
            else if (better(o, oi, b2, i2)) { b2 = o; i2 = oi; }
        }
        size_t off = ((size_t)(r0 + tid) * NCB + blockIdx.x) * 2;
        pval[off] = b1;     pidx[off] = i1;
        pval[off + 1] = b2; pidx[off + 1] = i2;
    }
}

// ---------------------------------------------------------------------------
// Kernel D: top-8 candidates per row from the 500 partials (approx ranking)
// ---------------------------------------------------------------------------
__global__ __launch_bounds__(256) void k_topk8(const float* __restrict__ pval,
                                               const int* __restrict__ pidx,
                                               int* __restrict__ cands) {
    int r = blockIdx.x, t = threadIdx.x;
    __shared__ float v[512];
    __shared__ int  id[512];
    for (int c = t; c < 512; c += 256) {
        if (c < NCB * 2) { v[c] = pval[(size_t)r * NCB * 2 + c]; id[c] = pidx[(size_t)r * NCB * 2 + c]; }
        else             { v[c] = NEG_INF; id[c] = 0x7fffffff; }
    }
    __syncthreads();
    if (t == 0) {
        float bv[NCAND]; int bi[NCAND];
#pragma unroll
        for (int j = 0; j < NCAND; ++j) { bv[j] = NEG_INF; bi[j] = 0x7fffffff; }
        for (int c = 0; c < NCB * 2; ++c) {
            float x = v[c]; int xi = id[c];
            if (better(x, xi, bv[NCAND - 1], bi[NCAND - 1])) {
                int j = NCAND - 1;
                while (j > 0 && better(x, xi, bv[j - 1], bi[j - 1])) {
                    bv[j] = bv[j - 1]; bi[j] = bi[j - 1]; --j;
                }
                bv[j] = x; bi[j] = xi;
            }
        }
#pragma unroll
        for (int j = 0; j < NCAND; ++j) cands[r * NCAND + j] = bi[j];
    }
}

// ---------------------------------------------------------------------------
// Kernel E: exact fp32 rescore of 8 candidates/row -> final top-2 + values
// ---------------------------------------------------------------------------
__global__ __launch_bounds__(256) void k_rescore(const float* __restrict__ s,
                                                 const float* __restrict__ T,
                                                 const int* __restrict__ cands,
                                                 const float* __restrict__ invw,
                                                 const float* __restrict__ invp,
                                                 float* __restrict__ outv,
                                                 int* __restrict__ tidx) {
    int r = blockIdx.x, t = threadIdx.x;
    int cg = t >> 5, l32 = t & 31;          // 8 groups of 32 lanes
    int c = cands[r * NCAND + cg];
    const float* Trow = T + (size_t)c * D_;
    const float* srow = s + (size_t)r * D_;
    float p = 0.f;
#pragma unroll
    for (int j = 0; j < 8; ++j) {
        int e = (j * 32 + l32) * 4;
        float4 a = *(const float4*)(srow + e);
        float4 b = *(const float4*)(Trow + e);
        p += a.x * b.x + a.y * b.y + a.z * b.z + a.w * b.w;
    }
#pragma unroll
    for (int off = 16; off >= 1; off >>= 1) p += __shfl_xor(p, off);  // stays in 32-group
    __shared__ float sc[NCAND];
    if (l32 == 0) sc[cg] = p;
    __syncthreads();
    if (t == 0) {
        float ip = invp[r];
        float b1 = NEG_INF, b2 = NEG_INF;
        int i1 = 0x7fffffff, i2 = 0x7fffffff;
#pragma unroll
        for (int j = 0; j < NCAND; ++j) {
            int ci = cands[r * NCAND + j];
            float val = sc[j] * invw[ci] * ip;
            if (better(val, ci, b1, i1)) { b2 = b1; i2 = i1; b1 = val; i1 = ci; }
            else if (better(val, ci, b2, i2)) { b2 = val; i2 = ci; }
        }
        outv[(size_t)r * 2 + 0] = b1;
        outv[(size_t)r * 2 + 1] = b2;
        tidx[r * 2 + 0] = i1;
        tidx[r * 2 + 1] = i2;
    }
}

// ---------------------------------------------------------------------------
// Kernel F: Z[r, 0:2, :] = T[idx], Z[r, 2:6, :] = P[r, :, :]
// ---------------------------------------------------------------------------
__global__ __launch_bounds__(256) void k_writeZ(const float* __restrict__ P,
                                                const float* __restrict__ T,
                                                const int* __restrict__ tidx,
                                                float* __restrict__ out) {
    int blk = blockIdx.x;  // r*6 + j
    int r = blk / 6, j = blk - r * 6;
    const float* src;
    if (j < KTOP) src = T + (size_t)tidx[r * 2 + j] * D_;
    else          src = P + ((size_t)r * NP_ + (j - KTOP)) * D_;
    float4 v = *(const float4*)(src + threadIdx.x * 4);
    *(float4*)(out + ((size_t)r * 6 + j) * D_ + threadIdx.x * 4) = v;
}

// ---------------------------------------------------------------------------
extern "C" void kernel_launch(void* const* d_in, const int* in_sizes, int n_in,
                              void* d_out, int out_size, void* d_ws, size_t ws_size,
                              hipStream_t stream) {
    const float* P   = (const float*)d_in[0];  // [32,64,4,1024]
    const float* we  = (const float*)d_in[1];  // [1024,768]
    const float* few = (const float*)d_in[2];  // [32000,768]
    const float* feb = (const float*)d_in[3];  // [32000]
    float* out = (float*)d_out;                // Z (12,582,912) then values (4096)
    float* ws  = (float*)d_ws;

    float* T    = ws + T_OFF;
    float* s    = ws + S_OFF;
    float* invw = ws + INVW_OFF;
    float* invp = ws + INVP_OFF;
    float* pval = ws + PV_OFF;
    int*   pidx = (int*)(ws + PI_OFF);
    unsigned short* sb = (unsigned short*)(ws + SB_OFF);
    unsigned short* Tb = (unsigned short*)(ws + TB_OFF);
    int*   cands = (int*)(ws + CAND_OFF);
    int*   tidx  = (int*)(ws + TIDX_OFF);
    float* outv = out + (size_t)R_ * 6 * D_;

    k_sum_pnorm<<<R_, 256, 0, stream>>>(P, s, sb, invp);
    k_gemm_T<<<dim3(D_ / 128, VC_ / 128), 256, 0, stream>>>(few, we, feb, T);
    k_wnorm<<<VC_, 256, 0, stream>>>(T, invw);
    k_make_tb<<<VC_, 128, 0, stream>>>(T, invw, Tb);
    k_scores_mfma<<<dim3(VC_ / 128, R_ / 128), 256, 0, stream>>>(Tb, sb, pval, pidx);
    k_topk8<<<R_, 256, 0, stream>>>(pval, pidx, cands);
    k_rescore<<<R_, 256, 0, stream>>>(s, T, cands, invw, invp, outv, tidx);
    k_writeZ<<<R_ * 6, 256, 0, stream>>>(P, T, tidx, out);
}

// Round 4
// 733.028 us; speedup vs baseline: 3.5176x; 1.5604x over previous
//
#include <hip/hip_runtime.h>
#include <hip/hip_bf16.h>
#include <math.h>

// Problem constants
#define B_    32
#define DIM_  64
#define NP_   4
#define D_    1024
#define E_    768
#define VC_   32000
#define R_    2048          // B_*DIM_
#define KTOP  2
#define EPS_  1e-8f
#define NCB   250           // 32000 / 128 v-blocks in scores GEMM
#define NCAND 8

// Workspace layout (float offsets), ~221 MB total
#define T_OFF    ((size_t)0)
#define S_OFF    (T_OFF + (size_t)VC_ * D_)          // 32,768,000
#define INVW_OFF (S_OFF + (size_t)R_ * D_)           // 34,865,152
#define INVP_OFF (INVW_OFF + VC_)
#define WSQ_OFF  (INVP_OFF + R_)
#define PV_OFF   (WSQ_OFF + VC_)
#define PI_OFF   (PV_OFF + (size_t)R_ * NCB * 2)
#define SB_OFF   (PI_OFF + (size_t)R_ * NCB * 2)     // ushort region, R_*D_ ushorts
#define TB_OFF   (SB_OFF + (size_t)R_ * D_ / 2)      // ushort region, VC_*D_ ushorts
#define WH_OFF   (TB_OFF + (size_t)VC_ * D_ / 2)     // ushort region, D_*E_ ushorts
#define WL_OFF   (WH_OFF + (size_t)D_ * E_ / 2)
#define CAND_OFF (WL_OFF + (size_t)D_ * E_ / 2)
#define TIDX_OFF (CAND_OFF + (size_t)R_ * NCAND)

#define NEG_INF (-3.4e38f)

typedef __bf16 bf16x8 __attribute__((ext_vector_type(8)));
typedef unsigned short u16x8 __attribute__((ext_vector_type(8)));
typedef float  f32x4  __attribute__((ext_vector_type(4)));

__device__ __forceinline__ unsigned short f2bf(float f) {
    unsigned u = __float_as_uint(f);
    u += 0x7fffu + ((u >> 16) & 1u);           // round-to-nearest-even
    return (unsigned short)(u >> 16);
}

// global -> LDS direct copy, 16B per lane. LDS dest = wave-uniform base + lane*16.
__device__ __forceinline__ void async_ld16(const void* gptr, void* lptr) {
    __builtin_amdgcn_global_load_lds(
        (const __attribute__((address_space(1))) void*)(uintptr_t)gptr,
        (__attribute__((address_space(3))) void*)(unsigned)(uintptr_t)lptr,
        16, 0, 0);
}

__device__ __forceinline__ bool better(float v, int i, float bv, int bi) {
    return (v > bv) || (v == bv && i < bi);
}

// ---------------------------------------------------------------------------
// Kernel Z0: zero the wsq accumulator (ws is poisoned before every launch)
// ---------------------------------------------------------------------------
__global__ __launch_bounds__(256) void k_zero(float* __restrict__ wsq) {
    int i = blockIdx.x * 256 + threadIdx.x;
    if (i < VC_) wsq[i] = 0.f;
}

// ---------------------------------------------------------------------------
// Kernel S0: split we (fp32 [D,E]) into bf16 hi/lo
// ---------------------------------------------------------------------------
__global__ __launch_bounds__(256) void k_split_we(const float* __restrict__ x,
                                                  unsigned short* __restrict__ hi,
                                                  unsigned short* __restrict__ lo) {
    int i = (blockIdx.x * 256 + threadIdx.x) * 4;   // grid sized exactly: D_*E_/1024 blocks
    float4 v = *(const float4*)(x + i);
    ushort4 h, l;
    float e;
    h.x = f2bf(v.x); e = v.x - __uint_as_float((unsigned)h.x << 16); l.x = f2bf(e);
    h.y = f2bf(v.y); e = v.y - __uint_as_float((unsigned)h.y << 16); l.y = f2bf(e);
    h.z = f2bf(v.z); e = v.z - __uint_as_float((unsigned)h.z << 16); l.z = f2bf(e);
    h.w = f2bf(v.w); e = v.w - __uint_as_float((unsigned)h.w << 16); l.w = f2bf(e);
    *(ushort4*)(hi + i) = h;
    *(ushort4*)(lo + i) = l;
}

// ---------------------------------------------------------------------------
// Kernel A: s[r,d] = sum_np P[r,np,d]; sb = bf16(s); invp[r] = 1/max(||P_r||,eps)
// ---------------------------------------------------------------------------
__global__ __launch_bounds__(256) void k_sum_pnorm(const float* __restrict__ P,
                                                   float* __restrict__ s,
                                                   unsigned short* __restrict__ sb,
                                                   float* __restrict__ invp) {
    int r = blockIdx.x;
    int t = threadIdx.x;
    const float* base = P + (size_t)r * NP_ * D_;
    float4 acc = make_float4(0.f, 0.f, 0.f, 0.f);
    float sq = 0.f;
#pragma unroll
    for (int np = 0; np < NP_; ++np) {
        float4 v = *(const float4*)(base + (size_t)np * D_ + t * 4);
        acc.x += v.x; acc.y += v.y; acc.z += v.z; acc.w += v.w;
        sq += v.x * v.x + v.y * v.y + v.z * v.z + v.w * v.w;
    }
    *(float4*)(s + (size_t)r * D_ + t * 4) = acc;
    ushort4 o;
    o.x = f2bf(acc.x); o.y = f2bf(acc.y); o.z = f2bf(acc.z); o.w = f2bf(acc.w);
    *(ushort4*)(sb + (size_t)r * D_ + t * 4) = o;

    __shared__ float red[256];
    red[t] = sq;
    __syncthreads();
    for (int off = 128; off > 0; off >>= 1) {
        if (t < off) red[t] += red[t + off];
        __syncthreads();
    }
    if (t == 0) invp[r] = 1.0f / fmaxf(sqrtf(red[0]), EPS_);
}

// ---------------------------------------------------------------------------
// Kernel B: split-bf16 MFMA GEMM.
//   T[v,d] = dot(few[v,:], we[d,:]) + bias[v]  via  Ah*Bh + Al*Bh + Ah*Bl
// A (few) staged fp32 via global_load_lds, split to hi/lo fragments in-register.
// B (we) pre-split bf16 hi/lo. Epilogue writes T (fp32), Tb (bf16) and
// accumulates per-row sumsq into wsq via atomics.
// Tile 128(v) x 128(d), BK=32, 4 waves.
// ---------------------------------------------------------------------------
__global__ __launch_bounds__(256) void k_gemm_T_mfma(const float* __restrict__ A,      // few [VC,E]
                                                     const unsigned short* __restrict__ Bh, // weh [D,E]
                                                     const unsigned short* __restrict__ Bl, // wel [D,E]
                                                     const float* __restrict__ bias,
                                                     float* __restrict__ T,
                                                     unsigned short* __restrict__ Tb,
                                                     float* __restrict__ wsq) {
    __shared__ __align__(16) float          Af[128 * 32];   // 16 KB, [v-row][k] fp32
    __shared__ __align__(16) unsigned short Bsh[128 * 32];  //  8 KB
    __shared__ __align__(16) unsigned short Bsl[128 * 32];  //  8 KB

    int tid = threadIdx.x;
    int wid = tid >> 6, lane = tid & 63;
    int quad = lane >> 4, l15 = lane & 15;
    int v0 = blockIdx.y * 128;
    int d0 = blockIdx.x * 128;
    int vband = (wid & 1) * 64, nband = (wid >> 1) * 64;

    f32x4 acc[4][4];
#pragma unroll
    for (int i = 0; i < 4; ++i)
#pragma unroll
        for (int j = 0; j < 4; ++j) acc[i][j] = f32x4{0.f, 0.f, 0.f, 0.f};

    int arow = wid * 32 + (lane >> 3);   // fp32 staging: 8 rows per wave-issue
    int acol = (lane & 7) * 4;           // float offset (16 B)
    int brow = wid * 32 + (lane >> 2);   // bf16 staging: 16 rows per wave-issue
    int bcol = (lane & 3) * 8;           // ushort offset (16 B)

    for (int k0 = 0; k0 < E_; k0 += 32) {
#pragma unroll
        for (int j = 0; j < 4; ++j)
            async_ld16(A + (size_t)(v0 + arow + j * 8) * E_ + k0 + acol,
                       (void*)(Af + (wid * 32 + j * 8) * 32));
#pragma unroll
        for (int j = 0; j < 2; ++j) {
            async_ld16(Bh + (size_t)(d0 + brow + j * 16) * E_ + k0 + bcol,
                       (void*)(Bsh + (wid * 32 + j * 16) * 32));
            async_ld16(Bl + (size_t)(d0 + brow + j * 16) * E_ + k0 + bcol,
                       (void*)(Bsl + (wid * 32 + j * 16) * 32));
        }
        __syncthreads();

        bf16x8 bh[4], bl[4];
#pragma unroll
        for (int nt = 0; nt < 4; ++nt) {
            bh[nt] = *(const bf16x8*)(Bsh + (nband + nt * 16 + l15) * 32 + quad * 8);
            bl[nt] = *(const bf16x8*)(Bsl + (nband + nt * 16 + l15) * 32 + quad * 8);
        }
#pragma unroll
        for (int mt = 0; mt < 4; ++mt) {
            const float* ap = Af + (vband + mt * 16 + l15) * 32 + quad * 8;
            f32x4 xa = *(const f32x4*)ap;
            f32x4 xb = *(const f32x4*)(ap + 4);
            u16x8 hu, lu;
#pragma unroll
            for (int e = 0; e < 4; ++e) {
                unsigned short h0 = f2bf(xa[e]);
                unsigned short h1 = f2bf(xb[e]);
                hu[e] = h0; hu[e + 4] = h1;
                lu[e]     = f2bf(xa[e] - __uint_as_float((unsigned)h0 << 16));
                lu[e + 4] = f2bf(xb[e] - __uint_as_float((unsigned)h1 << 16));
            }
            bf16x8 ah = __builtin_bit_cast(bf16x8, hu);
            bf16x8 al = __builtin_bit_cast(bf16x8, lu);
#pragma unroll
            for (int nt = 0; nt < 4; ++nt) {
                acc[mt][nt] = __builtin_amdgcn_mfma_f32_16x16x32_bf16(ah, bh[nt], acc[mt][nt], 0, 0, 0);
                acc[mt][nt] = __builtin_amdgcn_mfma_f32_16x16x32_bf16(al, bh[nt], acc[mt][nt], 0, 0, 0);
                acc[mt][nt] = __builtin_amdgcn_mfma_f32_16x16x32_bf16(ah, bl[nt], acc[mt][nt], 0, 0, 0);
            }
        }
        __syncthreads();
    }

    // Epilogue: T fp32, Tb bf16, row-sumsq partials -> wsq atomics
    float sq[4][4] = {};
#pragma unroll
    for (int mt = 0; mt < 4; ++mt) {
        int vbase = v0 + vband + mt * 16 + quad * 4;
        float bv[4];
#pragma unroll
        for (int rg = 0; rg < 4; ++rg) bv[rg] = bias[vbase + rg];
#pragma unroll
        for (int nt = 0; nt < 4; ++nt) {
            int d = d0 + nband + nt * 16 + l15;
#pragma unroll
            for (int rg = 0; rg < 4; ++rg) {
                float val = acc[mt][nt][rg] + bv[rg];
                T[(size_t)(vbase + rg) * D_ + d] = val;
                Tb[(size_t)(vbase + rg) * D_ + d] = f2bf(val);
                sq[mt][rg] += val * val;
            }
        }
    }
#pragma unroll
    for (int mt = 0; mt < 4; ++mt)
#pragma unroll
        for (int rg = 0; rg < 4; ++rg) {
            float p = sq[mt][rg];
            p += __shfl_xor(p, 1); p += __shfl_xor(p, 2);
            p += __shfl_xor(p, 4); p += __shfl_xor(p, 8);
            if (l15 == 0) atomicAdd(&wsq[v0 + vband + mt * 16 + quad * 4 + rg], p);
        }
}

// ---------------------------------------------------------------------------
// Kernel W: invw[v] = 1 / max(2*sqrt(wsq[v]), eps)
// ---------------------------------------------------------------------------
__global__ __launch_bounds__(256) void k_invw(const float* __restrict__ wsq,
                                              float* __restrict__ invw) {
    int v = blockIdx.x * 256 + threadIdx.x;
    if (v < VC_) invw[v] = 1.0f / fmaxf(2.0f * sqrtf(wsq[v]), EPS_);
}

// ---------------------------------------------------------------------------
// Kernel C: bf16 MFMA candidate GEMM. Tile 128(v) x 128(r), BK=32.
// Tb is UNSCALED bf16(T); invw applied in the epilogue before ranking.
// Emits per-(r, v-block) top-2 partials (approx values, used only to nominate).
// ---------------------------------------------------------------------------
__global__ __launch_bounds__(256) void k_scores_mfma(const unsigned short* __restrict__ Tb,
                                                     const unsigned short* __restrict__ sb,
                                                     const float* __restrict__ invw,
                                                     float* __restrict__ pval,
                                                     int* __restrict__ pidx) {
    __shared__ __align__(16) unsigned short As[128 * 32];  // [v-row][k]
    __shared__ __align__(16) unsigned short Bs[128 * 32];  // [r-row][k]
    __shared__ float mv[2][128][2];
    __shared__ int   mi[2][128][2];

    int tid = threadIdx.x;
    int wid = tid >> 6, lane = tid & 63;
    int quad = lane >> 4, l15 = lane & 15;
    int v0 = blockIdx.x * 128;
    int r0 = blockIdx.y * 128;
    int vband = (wid & 1) * 64, rband = (wid >> 1) * 64;

    f32x4 acc[4][4];
#pragma unroll
    for (int i = 0; i < 4; ++i)
#pragma unroll
        for (int j = 0; j < 4; ++j) acc[i][j] = f32x4{0.f, 0.f, 0.f, 0.f};

    int srow  = wid * 32 + (lane >> 2);
    int skoff = (lane & 3) * 8;

    for (int k0 = 0; k0 < D_; k0 += 32) {
#pragma unroll
        for (int j = 0; j < 2; ++j) {
            async_ld16(Tb + (size_t)(v0 + srow + j * 16) * D_ + k0 + skoff,
                       (void*)(As + (wid * 32 + j * 16) * 32));
            async_ld16(sb + (size_t)(r0 + srow + j * 16) * D_ + k0 + skoff,
                       (void*)(Bs + (wid * 32 + j * 16) * 32));
        }
        __syncthreads();
        bf16x8 af[4], bf[4];
#pragma unroll
        for (int mt = 0; mt < 4; ++mt)
            af[mt] = *(const bf16x8*)(As + (vband + mt * 16 + l15) * 32 + quad * 8);
#pragma unroll
        for (int nt = 0; nt < 4; ++nt)
            bf[nt] = *(const bf16x8*)(Bs + (rband + nt * 16 + l15) * 32 + quad * 8);
#pragma unroll
        for (int mt = 0; mt < 4; ++mt)
#pragma unroll
            for (int nt = 0; nt < 4; ++nt)
                acc[mt][nt] = __builtin_amdgcn_mfma_f32_16x16x32_bf16(af[mt], bf[nt], acc[mt][nt], 0, 0, 0);
        __syncthreads();
    }

    // Epilogue: scale by invw[v], per r top-2 over this block's 128 v's.
    float iw[4][4];
#pragma unroll
    for (int mt = 0; mt < 4; ++mt)
#pragma unroll
        for (int rg = 0; rg < 4; ++rg)
            iw[mt][rg] = invw[v0 + vband + mt * 16 + quad * 4 + rg];

#pragma unroll
    for (int nt = 0; nt < 4; ++nt) {
        float b1 = NEG_INF, b2 = NEG_INF;
        int i1 = 0x7fffffff, i2 = 0x7fffffff;
#pragma unroll
        for (int mt = 0; mt < 4; ++mt)
#pragma unroll
            for (int rg = 0; rg < 4; ++rg) {
                float val = acc[mt][nt][rg] * iw[mt][rg];
                int v = v0 + vband + mt * 16 + quad * 4 + rg;
                if (better(val, v, b1, i1)) { b2 = b1; i2 = i1; b1 = val; i1 = v; }
                else if (better(val, v, b2, i2)) { b2 = val; i2 = v; }
            }
#pragma unroll
        for (int off = 16; off <= 32; off <<= 1) {
            float o1 = __shfl_xor(b1, off), o2 = __shfl_xor(b2, off);
            int  oi1 = __shfl_xor(i1, off), oi2 = __shfl_xor(i2, off);
            if (better(o1, oi1, b1, i1)) {
                if (better(b1, i1, o2, oi2)) { b2 = b1; i2 = i1; } else { b2 = o2; i2 = oi2; }
                b1 = o1; i1 = oi1;
            } else if (better(o1, oi1, b2, i2)) { b2 = o1; i2 = oi1; }
        }
        if (quad == 0) {
            int rl = rband + nt * 16 + l15;
            mv[wid & 1][rl][0] = b1; mi[wid & 1][rl][0] = i1;
            mv[wid & 1][rl][1] = b2; mi[wid & 1][rl][1] = i2;
        }
    }
    __syncthreads();
    if (tid < 128) {
        float b1 = mv[0][tid][0], b2 = mv[0][tid][1];
        int   i1 = mi[0][tid][0], i2 = mi[0][tid][1];
#pragma unroll
        for (int sl = 0; sl < 2; ++sl) {
            float o = mv[1][tid][sl]; int oi = mi[1][tid][sl];
            if (better(o, oi, b1, i1)) { b2 = b1; i2 = i1; b1 = o; i1 = oi; }
            else if (better(o, oi, b2, i2)) { b2 = o; i2 = oi; }
        }
        size_t off = ((size_t)(r0 + tid) * NCB + blockIdx.x) * 2;
        pval[off] = b1;     pidx[off] = i1;
        pval[off + 1] = b2; pidx[off + 1] = i2;
    }
}

// ---------------------------------------------------------------------------
// Kernel D: top-8 candidates per row from the 500 partials (approx ranking)
// ---------------------------------------------------------------------------
__global__ __launch_bounds__(256) void k_topk8(const float* __restrict__ pval,
                                               const int* __restrict__ pidx,
                                               int* __restrict__ cands) {
    int r = blockIdx.x, t = threadIdx.x;
    __shared__ float v[512];
    __shared__ int  id[512];
    for (int c = t; c < 512; c += 256) {
        if (c < NCB * 2) { v[c] = pval[(size_t)r * NCB * 2 + c]; id[c] = pidx[(size_t)r * NCB * 2 + c]; }
        else             { v[c] = NEG_INF; id[c] = 0x7fffffff; }
    }
    __syncthreads();
    if (t == 0) {
        float bv[NCAND]; int bi[NCAND];
#pragma unroll
        for (int j = 0; j < NCAND; ++j) { bv[j] = NEG_INF; bi[j] = 0x7fffffff; }
        for (int c = 0; c < NCB * 2; ++c) {
            float x = v[c]; int xi = id[c];
            if (better(x, xi, bv[NCAND - 1], bi[NCAND - 1])) {
                int j = NCAND - 1;
                while (j > 0 && better(x, xi, bv[j - 1], bi[j - 1])) {
                    bv[j] = bv[j - 1]; bi[j] = bi[j - 1]; --j;
                }
                bv[j] = x; bi[j] = xi;
            }
        }
#pragma unroll
        for (int j = 0; j < NCAND; ++j) cands[r * NCAND + j] = bi[j];
    }
}

// ---------------------------------------------------------------------------
// Kernel E: exact fp32 rescore of 8 candidates/row -> final top-2 + values
// ---------------------------------------------------------------------------
__global__ __launch_bounds__(256) void k_rescore(const float* __restrict__ s,
                                                 const float* __restrict__ T,
                                                 const int* __restrict__ cands,
                                                 const float* __restrict__ invw,
                                                 const float* __restrict__ invp,
                                                 float* __restrict__ outv,
                                                 int* __restrict__ tidx) {
    int r = blockIdx.x, t = threadIdx.x;
    int cg = t >> 5, l32 = t & 31;          // 8 groups of 32 lanes
    int c = cands[r * NCAND + cg];
    const float* Trow = T + (size_t)c * D_;
    const float* srow = s + (size_t)r * D_;
    float p = 0.f;
#pragma unroll
    for (int j = 0; j < 8; ++j) {
        int e = (j * 32 + l32) * 4;
        float4 a = *(const float4*)(srow + e);
        float4 b = *(const float4*)(Trow + e);
        p += a.x * b.x + a.y * b.y + a.z * b.z + a.w * b.w;
    }
#pragma unroll
    for (int off = 16; off >= 1; off >>= 1) p += __shfl_xor(p, off);  // stays in 32-group
    __shared__ float sc[NCAND];
    if (l32 == 0) sc[cg] = p;
    __syncthreads();
    if (t == 0) {
        float ip = invp[r];
        float b1 = NEG_INF, b2 = NEG_INF;
        int i1 = 0x7fffffff, i2 = 0x7fffffff;
#pragma unroll
        for (int j = 0; j < NCAND; ++j) {
            int ci = cands[r * NCAND + j];
            float val = sc[j] * invw[ci] * ip;
            if (better(val, ci, b1, i1)) { b2 = b1; i2 = i1; b1 = val; i1 = ci; }
            else if (better(val, ci, b2, i2)) { b2 = val; i2 = ci; }
        }
        outv[(size_t)r * 2 + 0] = b1;
        outv[(size_t)r * 2 + 1] = b2;
        tidx[r * 2 + 0] = i1;
        tidx[r * 2 + 1] = i2;
    }
}

// ---------------------------------------------------------------------------
// Kernel F: Z[r, 0:2, :] = T[idx], Z[r, 2:6, :] = P[r, :, :]
// ---------------------------------------------------------------------------
__global__ __launch_bounds__(256) void k_writeZ(const float* __restrict__ P,
                                                const float* __restrict__ T,
                                                const int* __restrict__ tidx,
                                                float* __restrict__ out) {
    int blk = blockIdx.x;  // r*6 + j
    int r = blk / 6, j = blk - r * 6;
    const float* src;
    if (j < KTOP) src = T + (size_t)tidx[r * 2 + j] * D_;
    else          src = P + ((size_t)r * NP_ + (j - KTOP)) * D_;
    float4 v = *(const float4*)(src + threadIdx.x * 4);
    *(float4*)(out + ((size_t)r * 6 + j) * D_ + threadIdx.x * 4) = v;
}

// ---------------------------------------------------------------------------
extern "C" void kernel_launch(void* const* d_in, const int* in_sizes, int n_in,
                              void* d_out, int out_size, void* d_ws, size_t ws_size,
                              hipStream_t stream) {
    const float* P   = (const float*)d_in[0];  // [32,64,4,1024]
    const float* we  = (const float*)d_in[1];  // [1024,768]
    const float* few = (const float*)d_in[2];  // [32000,768]
    const float* feb = (const float*)d_in[3];  // [32000]
    float* out = (float*)d_out;                // Z (12,582,912) then values (4096)
    float* ws  = (float*)d_ws;

    float* T    = ws + T_OFF;
    float* s    = ws + S_OFF;
    float* invw = ws + INVW_OFF;
    float* invp = ws + INVP_OFF;
    float* wsq  = ws + WSQ_OFF;
    float* pval = ws + PV_OFF;
    int*   pidx = (int*)(ws + PI_OFF);
    unsigned short* sb  = (unsigned short*)(ws + SB_OFF);
    unsigned short* Tb  = (unsigned short*)(ws + TB_OFF);
    unsigned short* weh = (unsigned short*)(ws + WH_OFF);
    unsigned short* wel = (unsigned short*)(ws + WL_OFF);
    int*   cands = (int*)(ws + CAND_OFF);
    int*   tidx  = (int*)(ws + TIDX_OFF);
    float* outv = out + (size_t)R_ * 6 * D_;

    k_zero<<<(VC_ + 255) / 256, 256, 0, stream>>>(wsq);
    k_split_we<<<(D_ * E_) / 1024, 256, 0, stream>>>(we, weh, wel);
    k_sum_pnorm<<<R_, 256, 0, stream>>>(P, s, sb, invp);
    k_gemm_T_mfma<<<dim3(D_ / 128, VC_ / 128), 256, 0, stream>>>(few, weh, wel, feb, T, Tb, wsq);
    k_invw<<<(VC_ + 255) / 256, 256, 0, stream>>>(wsq, invw);
    k_scores_mfma<<<dim3(VC_ / 128, R_ / 128), 256, 0, stream>>>(Tb, sb, invw, pval, pidx);
    k_topk8<<<R_, 256, 0, stream>>>(pval, pidx, cands);
    k_rescore<<<R_, 256, 0, stream>>>(s, T, cands, invw, invp, outv, tidx);
    k_writeZ<<<R_ * 6, 256, 0, stream>>>(P, T, tidx, out);
}